// Round 9
// baseline (53.071 us; speedup 1.0000x reference)
//
#include <hip/hip_runtime.h>
#include <hip/hip_fp16.h>

typedef _Float16 f16x2 __attribute__((ext_vector_type(2)));
typedef _Float16 f16x8 __attribute__((ext_vector_type(8)));
typedef float    f32x4 __attribute__((ext_vector_type(4)));
typedef unsigned u32x4 __attribute__((ext_vector_type(4)));
typedef unsigned u32x2 __attribute__((ext_vector_type(2)));

#define M_DIM   32
#define K_DIM   8192
#define N_DIM   28672
#define KWORDS  1024           // K/8 packed words per weight row
#define NKB     128            // K/64 scale blocks per row
#define NBLK_N  112            // N/256 n-blocks
#define NSPLIT  8
#define OUT_ELEMS (M_DIM * N_DIM)
#define X16_BYTES (KWORDS * M_DIM * 16)   // 512 KB fragment-layout x

__device__ __forceinline__ unsigned pkrtz(float a, float b) {
    return __builtin_bit_cast(unsigned, __builtin_amdgcn_cvt_pkrtz(a, b));
}

// x -> fragment-layout fp16: x16[w][m] = 8 fp16 of row m, pairs (k=8w+p, 8w+p+4)
// (identical k-permutation to the nibble unpack, so MFMA k-sums match)
__global__ __launch_bounds__(256) void x_transform(const float* __restrict__ x,
                                                   uint4* __restrict__ x16) {
    const int idx = blockIdx.x * 256 + threadIdx.x;   // w*32 + m
    const int w = idx >> 5, m = idx & 31;
    const float4* p = (const float4*)(x + (size_t)m * K_DIM + w * 8);
    float4 f0 = p[0], f1 = p[1];
    uint4 v = { pkrtz(f0.x, f1.x), pkrtz(f0.y, f1.y),
                pkrtz(f0.z, f1.z), pkrtz(f0.w, f1.w) };
    x16[idx] = v;
}

__global__ __launch_bounds__(256) void wql_init(const float* __restrict__ bias,
                                                float* __restrict__ out) {
    int n = blockIdx.x * 256 + threadIdx.x;
    int m = blockIdx.y;
    out[(size_t)m * N_DIM + n] = bias[n];
}

// 8 nibbles -> 8 dequantized fp16. Pair p = nibbles (p,p+4); 0x6400|q = 1024+q
// exact; cpk = -(1024+8+zq) exact; (f+cpk) exact small int; one rounding on *spk.
__device__ __forceinline__ f16x8 dq_word(unsigned W, f16x2 spk, f16x2 cpk) {
    union { f16x2 h[4]; f16x8 v; } r;
#pragma unroll
    for (int p = 0; p < 4; ++p) {
        unsigned raw = ((W >> (4 * p)) & 0x000F000Fu) | 0x64006400u;
        f16x2 f = __builtin_bit_cast(f16x2, raw);
        r.h[p] = (f + cpk) * spk;
    }
    return r.v;
}

// order-pinned global loads (asm volatile keeps issue order & can't be sunk)
#define GL_X4(dst, addr, OFF) \
    asm volatile("global_load_dwordx4 %0, %1, off offset:" #OFF \
                 : "=v"(dst) : "v"(addr))
#define GL_X2(dst, addr, OFF) \
    asm volatile("global_load_dwordx2 %0, %1, off offset:" #OFF \
                 : "=v"(dst) : "v"(addr))
#define WAIT_V(N) do { \
    asm volatile("s_waitcnt vmcnt(" #N ")" ::: "memory"); \
    __builtin_amdgcn_sched_barrier(0); } while (0)
#define SB0 __builtin_amdgcn_sched_barrier(0)

struct QW { u32x4 r0s0, r0s1, r1s0, r1s1; f32x4 sc0, sc1; };

// issue one chunk's qweight (4x dwordx4, chunk c at byte c*128 + {0,64})
// + scales (2x dwordx4, chunk c at byte c*16: 4 floats per 256-k chunk).
#define QWSC(Q, OQ0, OQ1, OS)                                                  \
    do {                                                                       \
        GL_X4((Q).r0s0, qb0, OQ0); GL_X4((Q).r0s1, qb0, OQ1);                  \
        GL_X4((Q).r1s0, qb1, OQ0); GL_X4((Q).r1s1, qb1, OQ1);                  \
        GL_X4((Q).sc0, sp0, OS);   GL_X4((Q).sc1, sp1, OS);                    \
        SB0;                                                                   \
    } while (0)

// stage chunk C of x16 (16 KB) into LDS buf C&1 (2x global_load_lds / thread)
#define STAGE(C)                                                               \
    do {                                                                       \
        const uint4* gs = x16 + ((size_t)ks * 4096 + (C) * 1024);              \
        __builtin_amdgcn_global_load_lds(                                      \
            (const __attribute__((address_space(1))) void*)(gs + tid),         \
            (__attribute__((address_space(3))) void*)(&xs[((C)&1)*1024 + tid]),\
            16, 0, 0);                                                         \
        __builtin_amdgcn_global_load_lds(                                      \
            (const __attribute__((address_space(1))) void*)(gs + 512 + tid),   \
            (__attribute__((address_space(3))) void*)(&xs[((C)&1)*1024 + 512 + tid]), \
            16, 0, 0);                                                         \
        SB0;                                                                   \
    } while (0)

// one 16-word section: dequant 4 words x 2 rows, 8 ds_reads, 16 MFMA
#define COMPUTE_S(C, S, W0, W1, SC0, SC1)                                      \
    {                                                                          \
        const int blk = 4 * (C) + 2 * (S);                                     \
        const unsigned zl0 = ((blk) & 8) ? zr0[1] : zr0[0];                    \
        const unsigned zl1 = ((blk) & 8) ? zr1[1] : zr1[0];                    \
        const int sh4 = 4 * ((blk) & 7) + 4 * gh;                              \
        const int zq0 = (int)((zl0 >> sh4) & 0xF);                             \
        const int zq1 = (int)((zl1 >> sh4) & 0xF);                             \
        const float sf0 = gh ? (SC0)[2*(S)+1] : (SC0)[2*(S)];                  \
        const float sf1 = gh ? (SC1)[2*(S)+1] : (SC1)[2*(S)];                  \
        const _Float16 h0 = (_Float16)sf0, h1 = (_Float16)sf1;                 \
        const f16x2 spk0 = { h0, h0 }, spk1 = { h1, h1 };                      \
        const _Float16 c0 = (_Float16)(-(float)(1032 + zq0));                  \
        const _Float16 c1 = (_Float16)(-(float)(1032 + zq1));                  \
        const f16x2 cpk0 = { c0, c0 }, cpk1 = { c1, c1 };                      \
        _Pragma("unroll")                                                      \
        for (int j = 0; j < 4; ++j) {                                          \
            const int wl = (S) * 16 + 4 * g + j;                               \
            f16x8 xb0 = __builtin_bit_cast(f16x8,                              \
                xs[((C)&1)*1024 + wl*32 + lr]);                                \
            f16x8 xb1 = __builtin_bit_cast(f16x8,                              \
                xs[((C)&1)*1024 + wl*32 + lr + 16]);                           \
            f16x8 a0 = dq_word((W0)[j], spk0, cpk0);                           \
            f16x8 a1 = dq_word((W1)[j], spk1, cpk1);                           \
            acc00 = __builtin_amdgcn_mfma_f32_16x16x32_f16(a0, xb0, acc00, 0,0,0); \
            acc01 = __builtin_amdgcn_mfma_f32_16x16x32_f16(a0, xb1, acc01, 0,0,0); \
            acc10 = __builtin_amdgcn_mfma_f32_16x16x32_f16(a1, xb0, acc10, 0,0,0); \
            acc11 = __builtin_amdgcn_mfma_f32_16x16x32_f16(a1, xb1, acc11, 0,0,0); \
        }                                                                      \
    }

#define COMPUTE(C, Q)                                                          \
    COMPUTE_S(C, 0, (Q).r0s0, (Q).r1s0, (Q).sc0, (Q).sc1)                      \
    COMPUTE_S(C, 1, (Q).r0s1, (Q).r1s1, (Q).sc0, (Q).sc1)

// 512 thr / 8 waves; wave covers 32 n-rows (2 sub-tiles), n-tile 256; M=32.
// K chunk = 256 (4 chunks/block, NSPLIT=8). Pipelined: iteration c issues
// bundle(c+1) = [stage 2, qw 4, sc 2], waits vmcnt(8) (bundle c landed),
// computes chunk c, waits vmcnt(6) (stage c+1 landed), raw s_barrier.
// Loads stay in flight across barriers; vmcnt never drains to 0 mid-loop.
template <bool ATOMIC>
__global__ __launch_bounds__(512, 2) void wql_main(
    const uint4* __restrict__ x16, const unsigned* __restrict__ qw,
    const float* __restrict__ scales, const unsigned* __restrict__ qzeros,
    float* __restrict__ outp)
{
    __shared__ uint4 xs[2048];            // 2 bufs x [32 words][32 m] = 32 KB

    const int tid  = threadIdx.x;
    const int bid  = blockIdx.x;
    const int nblk = bid % NBLK_N;
    const int ks   = bid / NBLK_N;
    const int n0   = nblk * 256;

    const int wv   = tid >> 6;            // 0..7
    const int lane = tid & 63;
    const int g    = lane >> 4;           // k-group 0..3
    const int lr   = lane & 15;
    const int gh   = g >> 1;
    const int r0   = n0 + wv * 32 + lr;   // n-row sub-tile 0
    const int r1   = r0 + 16;             // n-row sub-tile 1

    const char* qb0 = (const char*)(qw + (size_t)r0 * KWORDS + ks * 128 + 4 * g);
    const char* qb1 = (const char*)(qw + (size_t)r1 * KWORDS + ks * 128 + 4 * g);
    const char* sp0 = (const char*)(scales + (size_t)r0 * NKB + ks * 16);
    const char* sp1 = (const char*)(scales + (size_t)r1 * NKB + ks * 16);

    QW qA, qB;
    u32x2 zr0, zr1;

    // ---- prologue: B0 (stage0 + qwsc0) + zeros -> wait stage0 -> barrier ----
    STAGE(0);
    QWSC(qA, 0, 64, 0);
    {
        const char* zp0 = (const char*)(qzeros + (size_t)r0 * 16 + ks * 2);
        const char* zp1 = (const char*)(qzeros + (size_t)r1 * 16 + ks * 2);
        GL_X2(zr0, zp0, 0);
        GL_X2(zr1, zp1, 0);
    }
    SB0;
    WAIT_V(8);                            // stage0 done (qwsc0 + z still flying)
    __builtin_amdgcn_s_barrier();

    f32x4 acc00 = {0,0,0,0}, acc01 = {0,0,0,0};
    f32x4 acc10 = {0,0,0,0}, acc11 = {0,0,0,0};

    // ---- it 0: issue B1, compute chunk 0 ----
    STAGE(1);
    QWSC(qB, 128, 192, 16);
    WAIT_V(8);                            // qwsc0 + zeros landed (B1 in flight)
    COMPUTE(0, qA)
    WAIT_V(6);                            // stage1 landed (qwsc1 in flight)
    __builtin_amdgcn_s_barrier();

    // ---- it 1: issue B2, compute chunk 1 ----
    STAGE(2);
    QWSC(qA, 256, 320, 32);
    WAIT_V(8);                            // qwsc1 landed
    COMPUTE(1, qB)
    WAIT_V(6);                            // stage2 landed
    __builtin_amdgcn_s_barrier();

    // ---- it 2: issue B3, compute chunk 2 ----
    STAGE(3);
    QWSC(qB, 384, 448, 48);
    WAIT_V(8);                            // qwsc2 landed
    COMPUTE(2, qA)
    WAIT_V(6);                            // stage3 landed
    __builtin_amdgcn_s_barrier();

    // ---- it 3: compute chunk 3 (nothing left to issue) ----
    WAIT_V(0);
    COMPUTE(3, qB)

    // C/D: m = lane&15, n-within-16 = 4*(lane>>4)+reg (validated R1/R4/R6/R7)
    const size_t base = (size_t)lr * N_DIM + n0 + wv * 32 + 4 * g;
    if constexpr (ATOMIC) {
#pragma unroll
        for (int r = 0; r < 4; ++r) {
            atomicAdd(outp + base + r, acc00[r]);
            atomicAdd(outp + base + 16 + r, acc10[r]);
            atomicAdd(outp + base + (size_t)16 * N_DIM + r, acc01[r]);
            atomicAdd(outp + base + (size_t)16 * N_DIM + 16 + r, acc11[r]);
        }
    } else {
        float* dst = outp + (size_t)ks * OUT_ELEMS;
        *(f32x4*)(dst + base) = acc00;
        *(f32x4*)(dst + base + 16) = acc10;
        *(f32x4*)(dst + (size_t)16 * N_DIM + base) = acc01;
        *(f32x4*)(dst + (size_t)16 * N_DIM + base + 16) = acc11;
    }
}

// out = bias + sum of 8 split partials (partials L3-hot right after main)
__global__ __launch_bounds__(256) void wql_reduce(const float* __restrict__ ws,
                                                  const float* __restrict__ bias,
                                                  float* __restrict__ out) {
    const int i4 = (blockIdx.x * 256 + threadIdx.x) * 4;
    const int n  = i4 % N_DIM;
    f32x4 acc = *(const f32x4*)(bias + n);
#pragma unroll
    for (int s = 0; s < NSPLIT; ++s)
        acc += *(const f32x4*)(ws + (size_t)s * OUT_ELEMS + i4);
    *(f32x4*)(out + i4) = acc;
}

extern "C" void kernel_launch(void* const* d_in, const int* in_sizes, int n_in,
                              void* d_out, int out_size, void* d_ws, size_t ws_size,
                              hipStream_t stream) {
    const float*    x      = (const float*)d_in[0];
    const unsigned* qwght  = (const unsigned*)d_in[1];
    const float*    scales = (const float*)d_in[2];
    const unsigned* qzeros = (const unsigned*)d_in[3];
    const float*    bias   = (const float*)d_in[4];
    float* out = (float*)d_out;

    uint4* x16 = (uint4*)d_ws;
    float* part = (float*)((char*)d_ws + X16_BYTES);
    const size_t need = X16_BYTES + (size_t)NSPLIT * OUT_ELEMS * sizeof(float);

    x_transform<<<dim3(KWORDS * M_DIM / 256), 256, 0, stream>>>(x, x16);
    if (ws_size >= need) {
        wql_main<false><<<dim3(NBLK_N * NSPLIT), 512, 0, stream>>>(
            x16, qwght, scales, qzeros, part);
        wql_reduce<<<dim3(OUT_ELEMS / 1024), 256, 0, stream>>>(
            part, bias, out);
    } else {
        wql_init<<<dim3(N_DIM / 256, M_DIM), 256, 0, stream>>>(bias, out);
        wql_main<true><<<dim3(NBLK_N * NSPLIT), 512, 0, stream>>>(
            x16, qwght, scales, qzeros, out);
    }
}